// Round 7
// baseline (223.720 us; speedup 1.0000x reference)
//
#include <hip/hip_runtime.h>
#include <cstddef>

// Problem constants (from reference)
#define BB 64
#define NN 207
#define KK 32
#define CC 8
#define DIN 64
#define DOUT 64
#define MM (BB * NN)         // 13248 flat positions; 13248 = 3312 * 4 exactly
#define PW 4                 // positions per wave (one 64-thread block = one wave)
#define NBLK (MM / PW)       // 3312 blocks, no clamping anywhere
#define IPAD 33              // idx row pad: 4 groups hit distinct banks
#define MPAD 68              // mean row stride: rows (c*4+p) -> bank offset 4p, disjoint

__device__ __forceinline__ float fast_tanh(float v) {
    // tanh(v) = 1 - 2/(exp(2v)+1); ~1e-6 rel err, saturates correctly.
    float e = __expf(2.0f * v);
    return 1.0f - 2.0f * __builtin_amdgcn_rcpf(e + 1.0f);
}

// ---- kernel 0: W[C][DOUT][DIN] -> Wt[C][DIN][DOUT] (one class per block) ----
__global__ __launch_bounds__(256) void transpose_W_kernel(
    const float* __restrict__ W, float* __restrict__ Wt)
{
    __shared__ float t[DIN * (DOUT + 1)];   // +1 pad: conflict-free transpose
    const int c   = blockIdx.x;
    const int tid = threadIdx.x;
    const float* __restrict__ Wc  = W  + (size_t)c * DOUT * DIN;
    float* __restrict__       Wtc = Wt + (size_t)c * DIN * DOUT;
    #pragma unroll
    for (int r = 0; r < 16; ++r) {
        const int i = r * 256 + tid;        // i = o*DIN + d  (coalesced read)
        const int o = i >> 6, d = i & 63;
        t[d * (DOUT + 1) + o] = Wc[i];
    }
    __syncthreads();
    #pragma unroll
    for (int r = 0; r < 16; ++r) {
        const int i = r * 256 + tid;        // i = d*DOUT + o (coalesced write)
        const int d = i >> 6, o = i & 63;
        Wtc[i] = t[d * (DOUT + 1) + o];
    }
}

// ---- main kernel: ONE WAVE PER BLOCK, 4 positions, ZERO block-wide barriers ----
// lane = (p = lane>>4 in 0..3, q4 = (lane&15)*4). Group p owns position m0+p
// end-to-end: phase 1 (class-bucketed sums + inline counts), means via
// wave-private LDS, phase 2 (per-class matvec + tanh). 3312 independent waves
// free-run -> phase-1 HBM streaming overlaps phase-2 VALU machine-wide.
template<bool USE_WT>
__global__ __launch_bounds__(64, 4) void ordered_gcn_kernel(
    const int* __restrict__ idx,      // [M, K]
    const float* __restrict__ x,      // [M, K, DIN]
    const float* __restrict__ W,      // [C, DOUT, DIN]
    const float* __restrict__ Wt,     // [C, DIN, DOUT] (in d_ws)
    float* __restrict__ out)          // [M, C, DOUT]
{
    __shared__ int   idx_s[PW * IPAD];        // 528 B
    __shared__ float mean_s[CC * PW * MPAD];  // 8704 B  (total ~9.2 KB/block)

    const int lane = threadIdx.x;
    const int m0   = blockIdx.x * PW;
    const int p    = lane >> 4;        // 0..3
    const int q4   = (lane & 15) * 4;  // d-slice (phase 1) / o-slice (phase 2)

    // ---- stage 4 idx rows: 128 ints, 2/lane, coalesced 512 B ----
    {
        const int i0 = lane, i1 = lane + 64;
        idx_s[(i0 >> 5) * IPAD + (i0 & 31)] = idx[(size_t)m0 * KK + i0];
        idx_s[(i1 >> 5) * IPAD + (i1 & 31)] = idx[(size_t)m0 * KK + i1];
    }
    __syncthreads();   // 1-wave block: compiles to a waitcnt, not a barrier stall

    // ---- phase 1: class-bucketed float4 sums + INLINE counts (reuses mf) ----
    const float* __restrict__ xp = x + (size_t)(m0 + p) * KK * DIN + q4;
    const int* idx_row = &idx_s[p * IPAD];

    float4 acc[CC];
    float  cntf[CC];
    #pragma unroll
    for (int c = 0; c < CC; ++c) { acc[c] = make_float4(0.f, 0.f, 0.f, 0.f); cntf[c] = 0.f; }

    #pragma unroll 1   // 8 loads in flight per batch; fits the 128-VGPR budget (no spill)
    for (int g = 0; g < 4; ++g) {
        float4 v[8];
        #pragma unroll
        for (int j = 0; j < 8; ++j)
            v[j] = *(const float4*)(xp + (size_t)(g * 8 + j) * DIN);
        #pragma unroll
        for (int j = 0; j < 8; ++j) {
            const int ca = idx_row[g * 8 + j];
            #pragma unroll
            for (int cc_ = 0; cc_ < CC; ++cc_) {
                const float mf = (ca == cc_) ? 1.0f : 0.0f;  // 1 cmp/sel, 4 fma, 1 add
                cntf[cc_] += mf;                              // all 16 lanes of group agree
                acc[cc_].x = fmaf(mf, v[j].x, acc[cc_].x);
                acc[cc_].y = fmaf(mf, v[j].y, acc[cc_].y);
                acc[cc_].z = fmaf(mf, v[j].z, acc[cc_].z);
                acc[cc_].w = fmaf(mf, v[j].w, acc[cc_].w);
            }
        }
    }

    // ---- means -> wave-private LDS (row = c*PW+p: groups on disjoint banks) ----
    #pragma unroll
    for (int c = 0; c < CC; ++c) {
        const float s = 1.0f / fmaxf(cntf[c], 1.0f);   // clamp(count,1)
        float4 m;
        m.x = acc[c].x * s; m.y = acc[c].y * s;
        m.z = acc[c].z * s; m.w = acc[c].w * s;
        *(float4*)(&mean_s[(c * PW + p) * MPAD + q4]) = m;
    }
    __syncthreads();   // waitcnt only: orders own ds_writes before ds_reads

    // ---- phase 2: out[p][c][o] = tanh(sum_d mean[p][c][d] * Wt[c][d][o]) ----
    // Group p computes its position's full [C][DOUT]; mean reads are 16-lane
    // broadcasts, the 4 groups' rows sit 4 banks apart (conflict-free).
    #pragma unroll 1
    for (int c = 0; c < CC; ++c) {
        const float* mrow = &mean_s[(c * PW + p) * MPAD];
        float4 a = make_float4(0.f, 0.f, 0.f, 0.f);

        if (USE_WT) {
            const float* __restrict__ Wtc = Wt + (size_t)c * DIN * DOUT + q4;
            #pragma unroll 2
            for (int dc = 0; dc < 16; ++dc) {
                const float4 w0 = *(const float4*)(Wtc + (size_t)(dc * 4 + 0) * DOUT);
                const float4 w1 = *(const float4*)(Wtc + (size_t)(dc * 4 + 1) * DOUT);
                const float4 w2 = *(const float4*)(Wtc + (size_t)(dc * 4 + 2) * DOUT);
                const float4 w3 = *(const float4*)(Wtc + (size_t)(dc * 4 + 3) * DOUT);
                const float4 m  = *(const float4*)(mrow + dc * 4);
                a.x = fmaf(m.x, w0.x, a.x); a.y = fmaf(m.x, w0.y, a.y);
                a.z = fmaf(m.x, w0.z, a.z); a.w = fmaf(m.x, w0.w, a.w);
                a.x = fmaf(m.y, w1.x, a.x); a.y = fmaf(m.y, w1.y, a.y);
                a.z = fmaf(m.y, w1.z, a.z); a.w = fmaf(m.y, w1.w, a.w);
                a.x = fmaf(m.z, w2.x, a.x); a.y = fmaf(m.z, w2.y, a.y);
                a.z = fmaf(m.z, w2.z, a.z); a.w = fmaf(m.z, w2.w, a.w);
                a.x = fmaf(m.w, w3.x, a.x); a.y = fmaf(m.w, w3.y, a.y);
                a.z = fmaf(m.w, w3.z, a.z); a.w = fmaf(m.w, w3.w, a.w);
            }
        } else {
            // fallback: raw W layout (works without d_ws)
            const float* __restrict__ Wc = W + (size_t)c * DOUT * DIN;
            #pragma unroll 2
            for (int dc = 0; dc < 16; ++dc) {
                float4 w[4];
                #pragma unroll
                for (int j = 0; j < 4; ++j)
                    w[j] = *(const float4*)(Wc + (size_t)(q4 + j) * DIN + dc * 4);
                const float4 m = *(const float4*)(mrow + dc * 4);
                float* af = (float*)&a;
                #pragma unroll
                for (int j = 0; j < 4; ++j) {
                    af[j] = fmaf(m.x, w[j].x, af[j]);
                    af[j] = fmaf(m.y, w[j].y, af[j]);
                    af[j] = fmaf(m.z, w[j].z, af[j]);
                    af[j] = fmaf(m.w, w[j].w, af[j]);
                }
            }
        }

        float4 r;
        r.x = fast_tanh(a.x);
        r.y = fast_tanh(a.y);
        r.z = fast_tanh(a.z);
        r.w = fast_tanh(a.w);
        *(float4*)(out + ((size_t)(m0 + p) * CC + c) * DOUT + q4) = r;
    }
}

extern "C" void kernel_launch(void* const* d_in, const int* in_sizes, int n_in,
                              void* d_out, int out_size, void* d_ws, size_t ws_size,
                              hipStream_t stream) {
    const int*   idx = (const int*)d_in[0];    // clustered_index_topk [B,N,K] int32
    const float* x   = (const float*)d_in[1];  // weightedDinput_topk [B,N,K,DIN] f32
    const float* W   = (const float*)d_in[2];  // W [C,DOUT,DIN] f32
    float* out = (float*)d_out;                // [B,N,C,DOUT] f32
    float* Wt  = (float*)d_ws;                 // [C,DIN,DOUT] scratch
                                               // (ws poison fills are unconditional -> free)
    const size_t wt_bytes = (size_t)CC * DIN * DOUT * sizeof(float);  // 128 KB
    if (ws_size >= wt_bytes) {
        transpose_W_kernel<<<dim3(CC), dim3(256), 0, stream>>>(W, Wt);
        ordered_gcn_kernel<true><<<dim3(NBLK), dim3(64), 0, stream>>>(idx, x, W, Wt, out);
    } else {
        ordered_gcn_kernel<false><<<dim3(NBLK), dim3(64), 0, stream>>>(idx, x, W, Wt, out);
    }
}

// Round 12
// 186.377 us; speedup vs baseline: 1.2004x; 1.2004x over previous
//
#include <hip/hip_runtime.h>
#include <cstddef>

// Problem constants (from reference)
#define BB 64
#define NN 207
#define KK 32
#define CC 8
#define DIN 64
#define DOUT 64
#define TILE 16              // n-positions per block (best-known config, round 0)
#define NT ((NN + TILE - 1) / TILE)   // 13 tiles along N -> 832 blocks
#define MPAD 68              // mean row stride: phase-2 class rows 4 banks apart

__device__ __forceinline__ float fast_tanh(float v) {
    // tanh(v) = 1 - 2/(exp(2v)+1); ~1e-6 rel err, saturates correctly.
    float e = __expf(2.0f * v);
    return 1.0f - 2.0f * __builtin_amdgcn_rcpf(e + 1.0f);
}

// ---- kernel 0: W[C][DOUT][DIN] -> Wt[C][DIN][DOUT] (one class per block) ----
__global__ __launch_bounds__(256) void transpose_W_kernel(
    const float* __restrict__ W, float* __restrict__ Wt)
{
    __shared__ float t[DIN * (DOUT + 1)];   // +1 pad: conflict-free transpose
    const int c   = blockIdx.x;
    const int tid = threadIdx.x;
    const float* __restrict__ Wc  = W  + (size_t)c * DOUT * DIN;
    float* __restrict__       Wtc = Wt + (size_t)c * DIN * DOUT;
    #pragma unroll
    for (int r = 0; r < 16; ++r) {
        const int i = r * 256 + tid;        // i = o*DIN + d  (coalesced read)
        const int o = i >> 6, d = i & 63;
        t[d * (DOUT + 1) + o] = Wc[i];
    }
    __syncthreads();
    #pragma unroll
    for (int r = 0; r < 16; ++r) {
        const int i = r * 256 + tid;        // i = d*DOUT + o (coalesced write)
        const int d = i >> 6, o = i & 63;
        Wtc[i] = t[d * (DOUT + 1) + o];
    }
}

// ---- phase-1 helpers: static 2-buffer software pipeline (rule #20 safe) ----
__device__ __forceinline__ void pf8(float4 (&buf)[8],
                                    const float* __restrict__ xp, int g) {
    #pragma unroll
    for (int j = 0; j < 8; ++j)
        buf[j] = *(const float4*)(xp + (size_t)(g * 8 + j) * DIN);
}
__device__ __forceinline__ void cb8(float4 (&acc)[CC], const float4 (&buf)[8],
                                    const int* idx_row, int g) {
    #pragma unroll
    for (int j = 0; j < 8; ++j) {
        const int ca = idx_row[g * 8 + j];
        #pragma unroll
        for (int cc_ = 0; cc_ < CC; ++cc_) {
            const float mf = (ca == cc_) ? 1.0f : 0.0f;  // 1 cmp/sel + 4 fma per class
            acc[cc_].x = fmaf(mf, buf[j].x, acc[cc_].x);
            acc[cc_].y = fmaf(mf, buf[j].y, acc[cc_].y);
            acc[cc_].z = fmaf(mf, buf[j].z, acc[cc_].z);
            acc[cc_].w = fmaf(mf, buf[j].w, acc[cc_].w);
        }
    }
}

// ---- phase-2 helpers ----
__device__ __forceinline__ void wload(float4 (&w)[4],
                                      const float* __restrict__ Wtc, int dc) {
    #pragma unroll
    for (int j = 0; j < 4; ++j)
        w[j] = *(const float4*)(Wtc + (size_t)(dc * 4 + j) * DOUT);
}
__device__ __forceinline__ void wcompute(float4 (&acc2)[8], const float4 (&w)[4],
                                         const float* mean_base, int dc) {
    // mean_base = &mean_s[(ph*8*CC + c) * MPAD], stride per pos = CC*MPAD
    #pragma unroll
    for (int pp = 0; pp < 8; ++pp) {
        const float4 m = *(const float4*)(mean_base + (size_t)pp * CC * MPAD + dc * 4);
        acc2[pp].x = fmaf(m.x, w[0].x, acc2[pp].x);
        acc2[pp].y = fmaf(m.x, w[0].y, acc2[pp].y);
        acc2[pp].z = fmaf(m.x, w[0].z, acc2[pp].z);
        acc2[pp].w = fmaf(m.x, w[0].w, acc2[pp].w);
        acc2[pp].x = fmaf(m.y, w[1].x, acc2[pp].x);
        acc2[pp].y = fmaf(m.y, w[1].y, acc2[pp].y);
        acc2[pp].z = fmaf(m.y, w[1].z, acc2[pp].z);
        acc2[pp].w = fmaf(m.y, w[1].w, acc2[pp].w);
        acc2[pp].x = fmaf(m.z, w[2].x, acc2[pp].x);
        acc2[pp].y = fmaf(m.z, w[2].y, acc2[pp].y);
        acc2[pp].z = fmaf(m.z, w[2].z, acc2[pp].z);
        acc2[pp].w = fmaf(m.z, w[2].w, acc2[pp].w);
        acc2[pp].x = fmaf(m.w, w[3].x, acc2[pp].x);
        acc2[pp].y = fmaf(m.w, w[3].y, acc2[pp].y);
        acc2[pp].z = fmaf(m.w, w[3].z, acc2[pp].z);
        acc2[pp].w = fmaf(m.w, w[3].w, acc2[pp].w);
    }
}

// ---- main kernel ----
// __launch_bounds__(256, 2): min-waves hint 2/EU so the register allocator
// budgets up to ~256 VGPRs instead of targeting 8 waves/EU -> 64 VGPRs and
// SPILLING the pipeline buffers (round-6 failure: WRITE_SIZE +5 MB scratch).
// Occupancy is LDS-capped at 4 blocks/CU (37.4 KB) regardless, which needs
// only VGPR <= 128; expected allocation ~116.
template<bool USE_WT>
__global__ __launch_bounds__(256, 2) void ordered_gcn_kernel(
    const int* __restrict__ idx,      // [B, N, K]
    const float* __restrict__ x,      // [B, N, K, DIN]
    const float* __restrict__ W,      // [C, DOUT, DIN]
    const float* __restrict__ Wt,     // [C, DIN, DOUT] (in d_ws)
    float* __restrict__ out)          // [B, N, C, DOUT]
{
    __shared__ int   idx_s[TILE * KK];          // 2 KB
    __shared__ float inv_s[TILE * CC];          // 512 B
    __shared__ float mean_s[TILE * CC * MPAD];  // 34816 B

    const int tid = threadIdx.x;
    const int b  = blockIdx.y;
    const int n0 = blockIdx.x * TILE;

    // ---- load idx tile: 512 ints, 2 per thread, coalesced ----
    #pragma unroll
    for (int r = 0; r < 2; ++r) {
        const int i = r * 256 + tid;
        const int pq = i >> 5, k = i & 31;
        int n = n0 + pq; if (n > NN - 1) n = NN - 1;   // clamped rows never stored
        idx_s[i] = idx[((size_t)(b * NN + n)) * KK + k];
    }
    __syncthreads();

    // ---- per (pos, class) inverse clamped count (128 threads) ----
    if (tid < TILE * CC) {
        const int pp = tid >> 3, c = tid & 7;
        int cnt = 0;
        #pragma unroll
        for (int k = 0; k < KK; ++k) cnt += (idx_s[pp * KK + k] == c) ? 1 : 0;
        inv_s[tid] = 1.0f / (float)(cnt > 1 ? cnt : 1);
    }
    // (inv_s is consumed only after the next barrier)

    // ---- phase 1: class-bucketed float4 sums, 2-buffer pipelined loads ----
    // Loads for batch g+1 are ISSUED before batch g's compute, so only the
    // first batch pays full latency; later batches hide under ~800 cy of FMA.
    const int p  = tid >> 4;          // 0..15
    const int d4 = (tid & 15) * 4;
    {
        int n = n0 + p; if (n > NN - 1) n = NN - 1;
        const float* __restrict__ xp = x + ((size_t)(b * NN + n)) * KK * DIN + d4;
        const int* idx_row = &idx_s[p * KK];

        float4 acc[CC];
        #pragma unroll
        for (int c = 0; c < CC; ++c) acc[c] = make_float4(0.f, 0.f, 0.f, 0.f);

        float4 va[8], vb[8];
        pf8(va, xp, 0);
        pf8(vb, xp, 1);            // 16 loads in flight
        cb8(acc, va, idx_row, 0);
        pf8(va, xp, 2);
        cb8(acc, vb, idx_row, 1);
        pf8(vb, xp, 3);
        cb8(acc, va, idx_row, 2);
        cb8(acc, vb, idx_row, 3);

        __syncthreads();   // inv_s ready for all threads

        #pragma unroll
        for (int cc_ = 0; cc_ < CC; ++cc_) {
            const float s = inv_s[p * CC + cc_];
            float4 m;
            m.x = acc[cc_].x * s; m.y = acc[cc_].y * s;
            m.z = acc[cc_].z * s; m.w = acc[cc_].w * s;
            *(float4*)(&mean_s[(p * CC + cc_) * MPAD + d4]) = m;
        }
    }
    __syncthreads();

    // ---- phase 2: out[p][c][o] = tanh(sum_d mean[p][c][d] * Wt[c][d][o]) ----
    // thread = (ph = tid>>7 -> pos 8ph..8ph+7, c = (tid>>4)&7, o0 = (tid&15)*4).
    // W loads 2-buffer pipelined; tail peeled (no branch, no redundant load).
    {
        const int ph = tid >> 7;
        const int c  = (tid >> 4) & 7;
        const int o0 = (tid & 15) * 4;

        float4 acc2[8];
        #pragma unroll
        for (int pp = 0; pp < 8; ++pp) acc2[pp] = make_float4(0.f, 0.f, 0.f, 0.f);

        if (USE_WT) {
            const float* __restrict__ Wtc = Wt + (size_t)c * DIN * DOUT + o0;
            const float* mean_base = &mean_s[(ph * 8 * CC + c) * MPAD];

            float4 wa[4], wb[4];
            wload(wa, Wtc, 0);
            #pragma unroll 1
            for (int dc = 0; dc < 14; dc += 2) {
                wload(wb, Wtc, dc + 1);               // issue next rows
                wcompute(acc2, wa, mean_base, dc);    // compute current
                wload(wa, Wtc, dc + 2);
                wcompute(acc2, wb, mean_base, dc + 1);
            }
            wload(wb, Wtc, 15);                        // peeled tail
            wcompute(acc2, wa, mean_base, 14);
            wcompute(acc2, wb, mean_base, 15);
        } else {
            // fallback: raw W layout (scattered within wave, works without d_ws)
            const float* __restrict__ Wc = W + (size_t)c * DOUT * DIN;
            #pragma unroll 1
            for (int dc = 0; dc < 16; ++dc) {
                float4 w[4];
                #pragma unroll
                for (int j = 0; j < 4; ++j)
                    w[j] = *(const float4*)(Wc + (size_t)(o0 + j) * DIN + dc * 4);
                #pragma unroll
                for (int pp = 0; pp < 8; ++pp) {
                    const int pq = ph * 8 + pp;
                    const float4 m = *(const float4*)(&mean_s[(pq * CC + c) * MPAD + dc * 4]);
                    float* a = (float*)&acc2[pp];
                    #pragma unroll
                    for (int j = 0; j < 4; ++j) {
                        a[j] = fmaf(m.x, w[j].x, a[j]);
                        a[j] = fmaf(m.y, w[j].y, a[j]);
                        a[j] = fmaf(m.z, w[j].z, a[j]);
                        a[j] = fmaf(m.w, w[j].w, a[j]);
                    }
                }
            }
        }

        #pragma unroll
        for (int pp = 0; pp < 8; ++pp) {
            const int pq = ph * 8 + pp;
            const int nn = n0 + pq;
            if (nn < NN) {
                float4 r;
                r.x = fast_tanh(acc2[pp].x);
                r.y = fast_tanh(acc2[pp].y);
                r.z = fast_tanh(acc2[pp].z);
                r.w = fast_tanh(acc2[pp].w);
                *(float4*)(out + (((size_t)(b * NN + nn)) * CC + c) * DOUT + o0) = r;
            }
        }
    }
}

extern "C" void kernel_launch(void* const* d_in, const int* in_sizes, int n_in,
                              void* d_out, int out_size, void* d_ws, size_t ws_size,
                              hipStream_t stream) {
    const int*   idx = (const int*)d_in[0];    // clustered_index_topk [B,N,K] int32
    const float* x   = (const float*)d_in[1];  // weightedDinput_topk [B,N,K,DIN] f32
    const float* W   = (const float*)d_in[2];  // W [C,DOUT,DIN] f32
    float* out = (float*)d_out;                // [B,N,C,DOUT] f32
    float* Wt  = (float*)d_ws;                 // [C,DIN,DOUT] scratch
                                               // (ws poison fills are unconditional -> free)
    dim3 grid(NT, BB);   // 13 x 64 = 832 blocks
    dim3 block(256);
    const size_t wt_bytes = (size_t)CC * DIN * DOUT * sizeof(float);  // 128 KB
    if (ws_size >= wt_bytes) {
        transpose_W_kernel<<<dim3(CC), block, 0, stream>>>(W, Wt);
        ordered_gcn_kernel<true><<<grid, block, 0, stream>>>(idx, x, W, Wt, out);
    } else {
        ordered_gcn_kernel<false><<<grid, block, 0, stream>>>(idx, x, W, Wt, out);
    }
}